// Round 10
// baseline (189.899 us; speedup 1.0000x reference)
//
#include <hip/hip_runtime.h>
#include <hip/hip_bf16.h>
#include <cstdint>
#include <cstddef>

#define B_  2
#define N_  2048
#define D_  1024
#define H_  16
#define DH_ 64
#define E3_ 192   // 3*DH

typedef __attribute__((ext_vector_type(8))) short short8;
typedef __attribute__((ext_vector_type(8))) unsigned short ushort8v;
typedef __attribute__((ext_vector_type(4))) float floatx4;

static __device__ __forceinline__ unsigned short f2bf(float f) {
  union { float f; unsigned u; } c; c.f = f;
  unsigned r = c.u + 0x7fffu + ((c.u >> 16) & 1u);   // RNE
  return (unsigned short)(r >> 16);
}

#define MFMA(a,b,c) __builtin_amdgcn_mfma_f32_16x16x32_bf16((a),(b),(c),0,0,0)

// async global->LDS, 16B per lane, dest = uniform base + lane*16
#define GL_LDS16(g, l) __builtin_amdgcn_global_load_lds( \
    (const __attribute__((address_space(1))) void*)(g),  \
    (__attribute__((address_space(3))) void*)(l), 16, 0, 0)

// ---------------- convert fp32 -> bf16 (straight) ----------------
__global__ __launch_bounds__(256) void k_f2bf(const float* __restrict__ in,
                                              unsigned short* __restrict__ out, int n8) {
  int i = blockIdx.x * blockDim.x + threadIdx.x;
  if (i >= n8) return;
  const float4* p = (const float4*)in + (size_t)i * 2;
  float4 a = p[0], b = p[1];
  ushort8v o;
  o[0]=f2bf(a.x); o[1]=f2bf(a.y); o[2]=f2bf(a.z); o[3]=f2bf(a.w);
  o[4]=f2bf(b.x); o[5]=f2bf(b.y); o[6]=f2bf(b.z); o[7]=f2bf(b.w);
  *((ushort8v*)out + i) = o;
}

// ---- W_kqv [h][d][e] -> Wt [cat][h][e'][d] bf16 (flat [3072][1024]) --------
__global__ __launch_bounds__(256) void k_twkqv(const float* __restrict__ W,
                                               unsigned short* __restrict__ Wt) {
  __shared__ float tile[64][65];
  int h = blockIdx.z, cat = blockIdx.y, e0 = cat * 64, d0 = blockIdx.x * 64;
  int t = threadIdx.x;
  const float* Wp = W + (size_t)h * D_ * E3_;
  int dr = t >> 2, ec = (t & 3) * 16;
#pragma unroll
  for (int j = 0; j < 16; j += 4) {
    float4 wv = *(const float4*)&Wp[(size_t)(d0 + dr) * E3_ + e0 + ec + j];
    tile[dr][ec + j + 0] = wv.x; tile[dr][ec + j + 1] = wv.y;
    tile[dr][ec + j + 2] = wv.z; tile[dr][ec + j + 3] = wv.w;
  }
  __syncthreads();
  int er = t >> 2, dc = (t & 3) * 16;
  ushort8v o0, o1;
#pragma unroll
  for (int j = 0; j < 8; j++) o0[j] = f2bf(tile[dc + j][er]);
#pragma unroll
  for (int j = 0; j < 8; j++) o1[j] = f2bf(tile[dc + 8 + j][er]);
  size_t o = ((size_t)(cat * 1024 + h * 64 + er)) * D_ + d0 + dc;
  *(ushort8v*)&Wt[o]     = o0;
  *(ushort8v*)&Wt[o + 8] = o1;
}

// ---------------- QKV projection GEMM, 128x128 tile, double-pumped BK=64 ----
__global__ __launch_bounds__(256) void k_qkv(const unsigned short* __restrict__ Xb,
                                             const unsigned short* __restrict__ Wt,
                                             const float* __restrict__ bkqv,
                                             unsigned short* __restrict__ Qb,
                                             unsigned short* __restrict__ Kb,
                                             unsigned short* __restrict__ Vt) {
  __shared__ unsigned short Alds[2][128 * 32];
  __shared__ unsigned short Blds[2][128 * 32];
  int t = threadIdx.x;
  int m0 = blockIdx.x * 128, c0 = blockIdx.y * 128;
  int wave = t >> 6, lane = t & 63, quad = lane >> 4, l16 = lane & 15;
  int wm = (wave >> 1) * 64, wn = (wave & 1) * 64;
  floatx4 acc[4][4];
#pragma unroll
  for (int i = 0; i < 4; i++)
#pragma unroll
    for (int j = 0; j < 4; j++) acc[i][j] = (floatx4){0.f, 0.f, 0.f, 0.f};

  const unsigned short* gA = Xb + (size_t)(m0 + wave * 32 + (lane >> 2)) * D_ + (lane & 3) * 8;
  const unsigned short* gB = Wt + (size_t)(c0 + wave * 32 + (lane >> 2)) * D_ + (lane & 3) * 8;
  unsigned short* lA0 = &Alds[0][(wave * 32) * 32];
  unsigned short* lA1 = &Alds[1][(wave * 32) * 32];
  unsigned short* lB0 = &Blds[0][(wave * 32) * 32];
  unsigned short* lB1 = &Blds[1][(wave * 32) * 32];

  for (int k0 = 0; k0 < D_; k0 += 64) {
    GL_LDS16(gA + k0,                 lA0);
    GL_LDS16(gA + k0 + 16 * D_,       lA0 + 16 * 32);
    GL_LDS16(gA + k0 + 32,            lA1);
    GL_LDS16(gA + k0 + 32 + 16 * D_,  lA1 + 16 * 32);
    GL_LDS16(gB + k0,                 lB0);
    GL_LDS16(gB + k0 + 16 * D_,       lB0 + 16 * 32);
    GL_LDS16(gB + k0 + 32,            lB1);
    GL_LDS16(gB + k0 + 32 + 16 * D_,  lB1 + 16 * 32);
    __syncthreads();
#pragma unroll
    for (int kk = 0; kk < 2; kk++) {
      short8 a[4], b[4];
#pragma unroll
      for (int mi = 0; mi < 4; mi++) a[mi] = *(const short8*)&Alds[kk][(wm + mi * 16 + l16) * 32 + quad * 8];
#pragma unroll
      for (int ni = 0; ni < 4; ni++) b[ni] = *(const short8*)&Blds[kk][(wn + ni * 16 + l16) * 32 + quad * 8];
#pragma unroll
      for (int mi = 0; mi < 4; mi++)
#pragma unroll
        for (int ni = 0; ni < 4; ni++) acc[mi][ni] = MFMA(a[mi], b[ni], acc[mi][ni]);
    }
    __syncthreads();
  }

  int cat = c0 >> 10;   // block-uniform: 0=K 1=Q 2=V
#pragma unroll
  for (int mi = 0; mi < 4; mi++)
#pragma unroll
    for (int ni = 0; ni < 4; ni++) {
      int colp = c0 + wn + ni * 16 + l16;       // permuted col
      int h = (colp >> 6) & 15;
      int e = colp & 63;
      int grow = m0 + wm + mi * 16 + quad * 4;  // 0..4095 = b*N + n
      int b = grow >> 11, n0 = grow & (N_ - 1);
      int bh = b * H_ + h;
      float bias = bkqv[h * E3_ + cat * 64 + e];
      floatx4 v = acc[mi][ni];
      if (cat == 0) {             // K
        size_t base = ((size_t)bh * N_ + n0) * DH_ + e;
#pragma unroll
        for (int r = 0; r < 4; r++) Kb[base + (size_t)r * DH_] = f2bf(v[r] + bias);
      } else if (cat == 1) {      // Q, pre-scaled by 1/8
        size_t base = ((size_t)bh * N_ + n0) * DH_ + e;
#pragma unroll
        for (int r = 0; r < 4; r++) Qb[base + (size_t)r * DH_] = f2bf((v[r] + bias) * 0.125f);
      } else {                    // V -> transposed [dh][n]
        ushort4 pk;
        pk.x = f2bf(v[0] + bias); pk.y = f2bf(v[1] + bias);
        pk.z = f2bf(v[2] + bias); pk.w = f2bf(v[3] + bias);
        *(ushort4*)&Vt[((size_t)bh * DH_ + e) * N_ + n0] = pk;
      }
    }
}

// ---------------- flash attention v6: kv-parity wave groups -----------------
// 64 q-rows/block (grid 1024 = 3/CU). Waves split in 2 groups by kv-tile
// parity (pure associative sum, m=0); each wave covers 32 q-rows (2 subtiles)
// -> K/V frag reads amortize 2x vs v3/v5 and barriers halve (2 per tile-pair).
// Group partials (O, l) combine through recycled K/V LDS at the end.
#define PSTR 72
__global__ __launch_bounds__(256) void k_flash(const unsigned short* __restrict__ Qb,
                                               const unsigned short* __restrict__ Kb,
                                               const unsigned short* __restrict__ Vt,
                                               unsigned short* __restrict__ sab) {
  int bh = blockIdx.x;
  int yr = blockIdx.y, g4 = yr >> 3, o = yr & 7;
  int qb = (g4 == 0) ? o : (g4 == 1) ? 31 - o : (g4 == 2) ? 8 + o : 23 - o;
  int q0b = qb * 64;
  int wave = threadIdx.x >> 6;
  int grp = wave >> 1, sub = wave & 1;           // grp: kv parity; sub: q half
  int lane = threadIdx.x & 63, quad = lane >> 4, l16 = lane & 15;
  const unsigned short* Qp = Qb + (size_t)bh * N_ * DH_;
  const unsigned short* Kp = Kb + (size_t)bh * N_ * DH_;
  const unsigned short* Vp = Vt + (size_t)bh * DH_ * N_;
  __shared__ unsigned short Klds[2][2 * 64 * 32];   // [parity][half][row][32]
  __shared__ unsigned short Vlds[2][2 * 64 * 32];
  __shared__ unsigned short Plds[4][16 * PSTR];     // per-wave private
  unsigned short* P = Plds[wave];

  short8 qf[2][2];
#pragma unroll
  for (int st = 0; st < 2; st++) {
    int qw = q0b + sub * 32 + st * 16;
    qf[st][0] = *(const short8*)&Qp[(qw + l16) * DH_ + quad * 8];
    qf[st][1] = *(const short8*)&Qp[(qw + l16) * DH_ + 32 + quad * 8];
  }
  const unsigned short* gK = Kp + (size_t)(wave * 16 + (lane >> 2)) * DH_ + (lane & 3) * 8;
  const unsigned short* gV = Vp + (size_t)(wave * 16 + (lane >> 2)) * N_ + (lane & 3) * 8;
  int lofs = (wave * 16) * 32;

  floatx4 O[2][4];
  float lr[2][4];
#pragma unroll
  for (int st = 0; st < 2; st++)
#pragma unroll
    for (int r = 0; r < 4; r++) { O[st][r] = (floatx4){0.f, 0.f, 0.f, 0.f}; lr[st][r] = 0.f; }

  int nt = qb + 1, npairs = (nt + 1) >> 1;
  for (int j = 0; j < npairs; j++) {
    if (j) __syncthreads();                     // pair j-1 reads done
    int t0 = 2 * j;
    {
      size_t ko = (size_t)(t0 * 64) * DH_;
      GL_LDS16(gK + ko,          &Klds[0][lofs]);
      GL_LDS16(gK + ko + 32,     &Klds[0][lofs + 64 * 32]);
      GL_LDS16(gV + t0 * 64,      &Vlds[0][lofs]);
      GL_LDS16(gV + t0 * 64 + 32, &Vlds[0][lofs + 64 * 32]);
    }
    if (t0 + 1 < nt) {
      size_t ko = (size_t)((t0 + 1) * 64) * DH_;
      GL_LDS16(gK + ko,          &Klds[1][lofs]);
      GL_LDS16(gK + ko + 32,     &Klds[1][lofs + 64 * 32]);
      GL_LDS16(gV + (t0+1) * 64,      &Vlds[1][lofs]);
      GL_LDS16(gV + (t0+1) * 64 + 32, &Vlds[1][lofs + 64 * 32]);
    }
    __syncthreads();                            // pair j staged
    int t = t0 + grp;
    if (t < nt) {
      short8 kf[4][2], vf[4][2];
#pragma unroll
      for (int c = 0; c < 4; c++) {
        kf[c][0] = *(const short8*)&Klds[grp][(c * 16 + l16) * 32 + quad * 8];
        kf[c][1] = *(const short8*)&Klds[grp][(64 + c * 16 + l16) * 32 + quad * 8];
        vf[c][0] = *(const short8*)&Vlds[grp][(c * 16 + l16) * 32 + quad * 8];
        vf[c][1] = *(const short8*)&Vlds[grp][(64 + c * 16 + l16) * 32 + quad * 8];
      }
#pragma unroll
      for (int st = 0; st < 2; st++) {
        floatx4 s[4];
#pragma unroll
        for (int c = 0; c < 4; c++) {
          s[c] = (floatx4){0.f, 0.f, 0.f, 0.f};
          s[c] = MFMA(qf[st][0], kf[c][0], s[c]);
          s[c] = MFMA(qf[st][1], kf[c][1], s[c]);
        }
        if (t == nt - 1) {                      // diagonal tile: mask col > row
#pragma unroll
          for (int c = 0; c < 4; c++)
#pragma unroll
            for (int r = 0; r < 4; r++) {
              int row = sub * 32 + st * 16 + quad * 4 + r;   // block-relative
              if (c * 16 + l16 > row) s[c][r] = -1e30f;
            }
        }
#pragma unroll
        for (int c = 0; c < 4; c++)
#pragma unroll
          for (int r = 0; r < 4; r++)
            s[c][r] = __builtin_amdgcn_exp2f(s[c][r] * 1.44269504f);
#pragma unroll
        for (int r = 0; r < 4; r++)
          lr[st][r] += (s[0][r] + s[1][r]) + (s[2][r] + s[3][r]);
        // P: C-layout -> LDS -> A-layout, wave-private (lgkm fence only)
#pragma unroll
        for (int c = 0; c < 4; c++)
#pragma unroll
          for (int r = 0; r < 4; r++)
            P[(quad * 4 + r) * PSTR + c * 16 + l16] = f2bf(s[c][r]);
        __asm__ volatile("s_waitcnt lgkmcnt(0)" ::: "memory");
        short8 pa0 = *(const short8*)&P[l16 * PSTR + quad * 8];
        short8 pa1 = *(const short8*)&P[l16 * PSTR + 32 + quad * 8];
        __asm__ volatile("" ::: "memory");      // later P writes stay below reads
#pragma unroll
        for (int dt = 0; dt < 4; dt++) {
          O[st][dt] = MFMA(pa0, vf[dt][0], O[st][dt]);
          O[st][dt] = MFMA(pa1, vf[dt][1], O[st][dt]);
        }
      }
    }
  }
  // row sums: reduce over the 16 lanes of each quad
#pragma unroll
  for (int m = 1; m < 16; m <<= 1)
#pragma unroll
    for (int st = 0; st < 2; st++)
#pragma unroll
      for (int r = 0; r < 4; r++) lr[st][r] += __shfl_xor(lr[st][r], m);

  __syncthreads();                              // all K/V reads done -> recycle LDS
  float* OF = (float*)&Klds[0][0];              // 16 KB = 4096 floats
  float* LF = (float*)&Vlds[0][0];
  if (wave >= 2) {                              // grp 1 stages partials
#pragma unroll
    for (int st = 0; st < 2; st++)
#pragma unroll
      for (int dt = 0; dt < 4; dt++)
        *(floatx4*)&OF[(((sub * 2 + st) * 4 + dt) << 8) + lane * 4] = O[st][dt];
    if (l16 == 0)
#pragma unroll
      for (int st = 0; st < 2; st++)
#pragma unroll
        for (int r = 0; r < 4; r++) LF[(sub * 2 + st) * 16 + quad * 4 + r] = lr[st][r];
  }
  __syncthreads();
  if (wave < 2) {                               // grp 0 combines + writes
    int b = bh >> 4, h = bh & 15;
#pragma unroll
    for (int st = 0; st < 2; st++) {
#pragma unroll
      for (int dt = 0; dt < 4; dt++)
        O[st][dt] += *(const floatx4*)&OF[(((wave * 2 + st) * 4 + dt) << 8) + lane * 4];
#pragma unroll
      for (int r = 0; r < 4; r++) {
        float lt = lr[st][r] + LF[(wave * 2 + st) * 16 + quad * 4 + r];
        float inv = 1.0f / lt;
        size_t base = ((size_t)b * N_ + q0b + wave * 32 + st * 16 + quad * 4 + r) * D_ + h * DH_;
#pragma unroll
        for (int dt = 0; dt < 4; dt++) sab[base + dt * 16 + l16] = f2bf(O[st][dt][r] * inv);
      }
    }
  }
}

// ---------------- output projection GEMM: 64x64 tile, 1024 blocks -----------
// R8/R9 lesson: grid >= 4 blocks/CU beats bigger tiles at 2/CU.
__global__ __launch_bounds__(256) void k_proj(const unsigned short* __restrict__ sab,
                                              const unsigned short* __restrict__ Wpb,
                                              const float* __restrict__ bproj,
                                              float* __restrict__ out) {
  __shared__ unsigned short Alds[2][64 * 32];
  __shared__ unsigned short Blds[2][64 * 32];
  int t = threadIdx.x;
  int m0 = blockIdx.x * 64, c0 = blockIdx.y * 64;
  int wave = t >> 6, lane = t & 63, quad = lane >> 4, l16 = lane & 15;
  int wm = (wave >> 1) * 32, wn = (wave & 1) * 32;
  floatx4 acc[2][2];
#pragma unroll
  for (int i = 0; i < 2; i++) { acc[i][0] = (floatx4){0,0,0,0}; acc[i][1] = (floatx4){0,0,0,0}; }

  const unsigned short* gA = sab + (size_t)(m0 + wave * 16 + (lane >> 2)) * D_ + (lane & 3) * 8;
  const unsigned short* gB = Wpb + (size_t)(c0 + wave * 16 + (lane >> 2)) * D_ + (lane & 3) * 8;
  unsigned short* lA0 = &Alds[0][(wave * 16) * 32];
  unsigned short* lA1 = &Alds[1][(wave * 16) * 32];
  unsigned short* lB0 = &Blds[0][(wave * 16) * 32];
  unsigned short* lB1 = &Blds[1][(wave * 16) * 32];

  for (int k0 = 0; k0 < D_; k0 += 64) {
    GL_LDS16(gA + k0,      lA0);
    GL_LDS16(gA + k0 + 32, lA1);
    GL_LDS16(gB + k0,      lB0);
    GL_LDS16(gB + k0 + 32, lB1);
    __syncthreads();
#pragma unroll
    for (int kk = 0; kk < 2; kk++) {
      short8 a[2], b[2];
#pragma unroll
      for (int mi = 0; mi < 2; mi++) a[mi] = *(const short8*)&Alds[kk][(wm + mi * 16 + l16) * 32 + quad * 8];
#pragma unroll
      for (int ni = 0; ni < 2; ni++) b[ni] = *(const short8*)&Blds[kk][(wn + ni * 16 + l16) * 32 + quad * 8];
#pragma unroll
      for (int mi = 0; mi < 2; mi++)
#pragma unroll
        for (int ni = 0; ni < 2; ni++) acc[mi][ni] = MFMA(a[mi], b[ni], acc[mi][ni]);
    }
    __syncthreads();
  }
#pragma unroll
  for (int mi = 0; mi < 2; mi++)
#pragma unroll
    for (int ni = 0; ni < 2; ni++) {
      int col = c0 + wn + ni * 16 + l16;
      int grow = m0 + wm + mi * 16 + quad * 4;
      float bias = bproj[col];
#pragma unroll
      for (int r = 0; r < 4; r++)
        out[(size_t)(grow + r) * D_ + col] = acc[mi][ni][r] + bias;
    }
}

extern "C" void kernel_launch(void* const* d_in, const int* in_sizes, int n_in,
                              void* d_out, int out_size, void* d_ws, size_t ws_size,
                              hipStream_t stream) {
  const float* x     = (const float*)d_in[0];
  const float* Wkqv  = (const float*)d_in[1];
  const float* bkqv  = (const float*)d_in[2];
  const float* Wproj = (const float*)d_in[3];
  const float* bproj = (const float*)d_in[4];
  float* out = (float*)d_out;

  char* w = (char*)d_ws;
  unsigned short* Xb  = (unsigned short*)(w);                       // 8 MiB  [B*N][D]
  unsigned short* Wt  = (unsigned short*)(w + (8u  << 20));         // 6 MiB  [3072][1024] (cat-permuted)
  unsigned short* Wpb = (unsigned short*)(w + (14u << 20));         // 2 MiB  [D][D]
  unsigned short* Qb  = (unsigned short*)(w + (16u << 20));         // 8 MiB  [B*H][N][DH] (pre-scaled)
  unsigned short* Kb  = (unsigned short*)(w + (24u << 20));         // 8 MiB  [B*H][N][DH]
  unsigned short* Vt  = (unsigned short*)(w + (32u << 20));         // 8 MiB  [B*H][DH][N]
  unsigned short* sa  = (unsigned short*)(w + (40u << 20));         // 8 MiB  [B*N][D]

  k_f2bf<<<(B_ * N_ * D_ / 8 + 255) / 256, 256, 0, stream>>>(x, Xb, B_ * N_ * D_ / 8);
  k_twkqv<<<dim3(D_ / 64, 3, H_), 256, 0, stream>>>(Wkqv, Wt);
  k_f2bf<<<(D_ * D_ / 8 + 255) / 256, 256, 0, stream>>>(Wproj, Wpb, D_ * D_ / 8);
  k_qkv<<<dim3(B_ * N_ / 128, 3072 / 128), 256, 0, stream>>>(Xb, Wt, bkqv, Qb, Kb, Vt);
  k_flash<<<dim3(B_ * H_, N_ / 64), 256, 0, stream>>>(Qb, Kb, Vt, sa);
  k_proj<<<dim3(B_ * N_ / 64, D_ / 64), 256, 0, stream>>>(sa, Wpb, bproj, out);
}

// Round 11
// 185.721 us; speedup vs baseline: 1.0225x; 1.0225x over previous
//
#include <hip/hip_runtime.h>
#include <hip/hip_bf16.h>
#include <cstdint>
#include <cstddef>

#define B_  2
#define N_  2048
#define D_  1024
#define H_  16
#define DH_ 64
#define E3_ 192   // 3*DH

typedef __attribute__((ext_vector_type(8))) short short8;
typedef __attribute__((ext_vector_type(8))) unsigned short ushort8v;
typedef __attribute__((ext_vector_type(4))) float floatx4;

static __device__ __forceinline__ unsigned short f2bf(float f) {
  union { float f; unsigned u; } c; c.f = f;
  unsigned r = c.u + 0x7fffu + ((c.u >> 16) & 1u);   // RNE
  return (unsigned short)(r >> 16);
}

#define MFMA(a,b,c) __builtin_amdgcn_mfma_f32_16x16x32_bf16((a),(b),(c),0,0,0)

// async global->LDS, 16B per lane, dest = uniform base + lane*16
#define GL_LDS16(g, l) __builtin_amdgcn_global_load_lds( \
    (const __attribute__((address_space(1))) void*)(g),  \
    (__attribute__((address_space(3))) void*)(l), 16, 0, 0)

// ---------------- merged prep: x->bf16 | W_kqv transpose | Wproj->bf16 ------
// grid = 2048 (x) + 768 (twkqv) + 512 (Wproj)
__global__ __launch_bounds__(256) void k_prep(const float* __restrict__ x,
                                              const float* __restrict__ Wkqv,
                                              const float* __restrict__ Wproj,
                                              unsigned short* __restrict__ Xb,
                                              unsigned short* __restrict__ Wt,
                                              unsigned short* __restrict__ Wpb) {
  __shared__ float tile[64][65];
  int bx = blockIdx.x, t = threadIdx.x;
  if (bx < 2048 || bx >= 2816) {            // plain f2bf converts
    const float* in = (bx < 2048) ? x : Wproj;
    unsigned short* out = (bx < 2048) ? Xb : Wpb;
    int i = ((bx < 2048) ? bx : bx - 2816) * 256 + t;
    const float4* p = (const float4*)in + (size_t)i * 2;
    float4 a = p[0], b = p[1];
    ushort8v o;
    o[0]=f2bf(a.x); o[1]=f2bf(a.y); o[2]=f2bf(a.z); o[3]=f2bf(a.w);
    o[4]=f2bf(b.x); o[5]=f2bf(b.y); o[6]=f2bf(b.z); o[7]=f2bf(b.w);
    *((ushort8v*)out + i) = o;
    return;
  }
  // W_kqv [h][d][e] -> Wt [cat][h][e'][d]  (col' = cat*1024 + h*64 + e')
  int idx = bx - 2048;
  int d0 = (idx & 15) * 64, rem = idx >> 4;
  int cat = rem % 3, h = rem / 3, e0 = cat * 64;
  const float* Wp = Wkqv + (size_t)h * D_ * E3_;
  int dr = t >> 2, ec = (t & 3) * 16;
#pragma unroll
  for (int j = 0; j < 16; j += 4) {
    float4 wv = *(const float4*)&Wp[(size_t)(d0 + dr) * E3_ + e0 + ec + j];
    tile[dr][ec + j + 0] = wv.x; tile[dr][ec + j + 1] = wv.y;
    tile[dr][ec + j + 2] = wv.z; tile[dr][ec + j + 3] = wv.w;
  }
  __syncthreads();
  int er = t >> 2, dc = (t & 3) * 16;
  ushort8v o0, o1;
#pragma unroll
  for (int j = 0; j < 8; j++) o0[j] = f2bf(tile[dc + j][er]);
#pragma unroll
  for (int j = 0; j < 8; j++) o1[j] = f2bf(tile[dc + 8 + j][er]);
  size_t o = ((size_t)(cat * 1024 + h * 64 + er)) * D_ + d0 + dc;
  *(ushort8v*)&Wt[o]     = o0;
  *(ushort8v*)&Wt[o + 8] = o1;
}

// ------- QKV GEMM, 128x128 tile, BK=32, prefetch double-buffer --------------
// v5-proven rotation: top barrier -> stage tile i+1 into other buffer ->
// compute tile i. The next barrier's vmcnt drain lands after a full iteration
// of compute instead of immediately.
__global__ __launch_bounds__(256) void k_qkv(const unsigned short* __restrict__ Xb,
                                             const unsigned short* __restrict__ Wt,
                                             const float* __restrict__ bkqv,
                                             unsigned short* __restrict__ Qb,
                                             unsigned short* __restrict__ Kb,
                                             unsigned short* __restrict__ Vt) {
  __shared__ unsigned short Alds[2][128 * 32];
  __shared__ unsigned short Blds[2][128 * 32];
  int t = threadIdx.x;
  int m0 = blockIdx.x * 128, c0 = blockIdx.y * 128;
  int wave = t >> 6, lane = t & 63, quad = lane >> 4, l16 = lane & 15;
  int wm = (wave >> 1) * 64, wn = (wave & 1) * 64;
  floatx4 acc[4][4];
#pragma unroll
  for (int i = 0; i < 4; i++)
#pragma unroll
    for (int j = 0; j < 4; j++) acc[i][j] = (floatx4){0.f, 0.f, 0.f, 0.f};

  const unsigned short* gA = Xb + (size_t)(m0 + wave * 32 + (lane >> 2)) * D_ + (lane & 3) * 8;
  const unsigned short* gB = Wt + (size_t)(c0 + wave * 32 + (lane >> 2)) * D_ + (lane & 3) * 8;
  int lofs = (wave * 32) * 32;

  // prologue: stage k-tile 0 -> buf 0
  GL_LDS16(gA,            &Alds[0][lofs]);
  GL_LDS16(gA + 16 * D_,  &Alds[0][lofs + 16 * 32]);
  GL_LDS16(gB,            &Blds[0][lofs]);
  GL_LDS16(gB + 16 * D_,  &Blds[0][lofs + 16 * 32]);

  for (int i = 0; i < 32; i++) {
    int buf = i & 1;
    __syncthreads();          // stage i complete; buf^1 reads (iter i-1) done
    if (i + 1 < 32) {         // prefetch tile i+1 (drained at NEXT barrier)
      int k0 = (i + 1) * 32;
      GL_LDS16(gA + k0,            &Alds[buf ^ 1][lofs]);
      GL_LDS16(gA + k0 + 16 * D_,  &Alds[buf ^ 1][lofs + 16 * 32]);
      GL_LDS16(gB + k0,            &Blds[buf ^ 1][lofs]);
      GL_LDS16(gB + k0 + 16 * D_,  &Blds[buf ^ 1][lofs + 16 * 32]);
    }
    short8 a[4], b[4];
#pragma unroll
    for (int mi = 0; mi < 4; mi++) a[mi] = *(const short8*)&Alds[buf][(wm + mi * 16 + l16) * 32 + quad * 8];
#pragma unroll
    for (int ni = 0; ni < 4; ni++) b[ni] = *(const short8*)&Blds[buf][(wn + ni * 16 + l16) * 32 + quad * 8];
#pragma unroll
    for (int mi = 0; mi < 4; mi++)
#pragma unroll
      for (int ni = 0; ni < 4; ni++) acc[mi][ni] = MFMA(a[mi], b[ni], acc[mi][ni]);
  }

  int cat = c0 >> 10;   // block-uniform: 0=K 1=Q 2=V
#pragma unroll
  for (int mi = 0; mi < 4; mi++)
#pragma unroll
    for (int ni = 0; ni < 4; ni++) {
      int colp = c0 + wn + ni * 16 + l16;       // permuted col
      int h = (colp >> 6) & 15;
      int e = colp & 63;
      int grow = m0 + wm + mi * 16 + quad * 4;  // 0..4095 = b*N + n
      int b = grow >> 11, n0 = grow & (N_ - 1);
      int bh = b * H_ + h;
      float bias = bkqv[h * E3_ + cat * 64 + e];
      floatx4 v = acc[mi][ni];
      if (cat == 0) {             // K
        size_t base = ((size_t)bh * N_ + n0) * DH_ + e;
#pragma unroll
        for (int r = 0; r < 4; r++) Kb[base + (size_t)r * DH_] = f2bf(v[r] + bias);
      } else if (cat == 1) {      // Q, pre-scaled by 1/8
        size_t base = ((size_t)bh * N_ + n0) * DH_ + e;
#pragma unroll
        for (int r = 0; r < 4; r++) Qb[base + (size_t)r * DH_] = f2bf((v[r] + bias) * 0.125f);
      } else {                    // V -> transposed [dh][n]
        ushort4 pk;
        pk.x = f2bf(v[0] + bias); pk.y = f2bf(v[1] + bias);
        pk.z = f2bf(v[2] + bias); pk.w = f2bf(v[3] + bias);
        *(ushort4*)&Vt[((size_t)bh * DH_ + e) * N_ + n0] = pk;
      }
    }
}

// ---------------- flash attention v5 (R9-proven): dbuf K/V, 64 q-rows -------
#define PSTR 72
__global__ __launch_bounds__(256) void k_flash(const unsigned short* __restrict__ Qb,
                                               const unsigned short* __restrict__ Kb,
                                               const unsigned short* __restrict__ Vt,
                                               unsigned short* __restrict__ sab) {
  int bh = blockIdx.x;
  int yr = blockIdx.y, g = yr >> 3, o = yr & 7;
  int qb = (g == 0) ? o : (g == 1) ? 31 - o : (g == 2) ? 8 + o : 23 - o;
  int q0b = qb * 64;
  int wave = threadIdx.x >> 6;
  int lane = threadIdx.x & 63, quad = lane >> 4, l16 = lane & 15;
  const unsigned short* Qp = Qb + (size_t)bh * N_ * DH_;
  const unsigned short* Kp = Kb + (size_t)bh * N_ * DH_;
  const unsigned short* Vp = Vt + (size_t)bh * DH_ * N_;
  __shared__ unsigned short Klds[2][2 * 64 * 32];   // [buf][half][row][32]
  __shared__ unsigned short Vlds[2][2 * 64 * 32];
  __shared__ unsigned short Plds[4][16 * PSTR];     // per-wave private
  unsigned short* P = Plds[wave];

  int q0w = q0b + wave * 16;
  short8 qf0 = *(const short8*)&Qp[(q0w + l16) * DH_ + quad * 8];
  short8 qf1 = *(const short8*)&Qp[(q0w + l16) * DH_ + 32 + quad * 8];

  const unsigned short* gK = Kp + (size_t)(wave * 16 + (lane >> 2)) * DH_ + (lane & 3) * 8;
  const unsigned short* gV = Vp + (size_t)(wave * 16 + (lane >> 2)) * N_ + (lane & 3) * 8;
  int lofs = (wave * 16) * 32;

  floatx4 O[4];
  float lr[4];
#pragma unroll
  for (int r = 0; r < 4; r++) { O[r] = (floatx4){0.f, 0.f, 0.f, 0.f}; lr[r] = 0.f; }

  int nt = (q0b >> 6) + 1;
  GL_LDS16(gK,      &Klds[0][lofs]);
  GL_LDS16(gK + 32, &Klds[0][lofs + 64 * 32]);
  GL_LDS16(gV,      &Vlds[0][lofs]);
  GL_LDS16(gV + 32, &Vlds[0][lofs + 64 * 32]);

  for (int i = 0; i < nt; i++) {
    int buf = i & 1;
    __syncthreads();
    if (i + 1 < nt) {
      int kvn = (i + 1) << 6;
      GL_LDS16(gK + (size_t)kvn * DH_,      &Klds[buf ^ 1][lofs]);
      GL_LDS16(gK + (size_t)kvn * DH_ + 32, &Klds[buf ^ 1][lofs + 64 * 32]);
      GL_LDS16(gV + kvn,                    &Vlds[buf ^ 1][lofs]);
      GL_LDS16(gV + kvn + 32,               &Vlds[buf ^ 1][lofs + 64 * 32]);
    }
    short8 kf[4][2], vf[4][2];
#pragma unroll
    for (int c = 0; c < 4; c++) {
      kf[c][0] = *(const short8*)&Klds[buf][(c * 16 + l16) * 32 + quad * 8];
      kf[c][1] = *(const short8*)&Klds[buf][(64 + c * 16 + l16) * 32 + quad * 8];
      vf[c][0] = *(const short8*)&Vlds[buf][(c * 16 + l16) * 32 + quad * 8];
      vf[c][1] = *(const short8*)&Vlds[buf][(64 + c * 16 + l16) * 32 + quad * 8];
    }
    floatx4 s[4];
#pragma unroll
    for (int c = 0; c < 4; c++) {
      s[c] = (floatx4){0.f, 0.f, 0.f, 0.f};
      s[c] = MFMA(qf0, kf[c][0], s[c]);
      s[c] = MFMA(qf1, kf[c][1], s[c]);
    }
    if (i == nt - 1) {            // diagonal tile: mask col > row
#pragma unroll
      for (int c = 0; c < 4; c++)
#pragma unroll
        for (int r = 0; r < 4; r++) {
          int row = wave * 16 + quad * 4 + r;   // block-relative
          if (c * 16 + l16 > row) s[c][r] = -1e30f;
        }
    }
#pragma unroll
    for (int c = 0; c < 4; c++)
#pragma unroll
      for (int r = 0; r < 4; r++)
        s[c][r] = __builtin_amdgcn_exp2f(s[c][r] * 1.44269504f);
#pragma unroll
    for (int r = 0; r < 4; r++)
      lr[r] += (s[0][r] + s[1][r]) + (s[2][r] + s[3][r]);
#pragma unroll
    for (int c = 0; c < 4; c++)
#pragma unroll
      for (int r = 0; r < 4; r++)
        P[(quad * 4 + r) * PSTR + c * 16 + l16] = f2bf(s[c][r]);
    __asm__ volatile("s_waitcnt lgkmcnt(0)" ::: "memory");
    short8 pa0 = *(const short8*)&P[l16 * PSTR + quad * 8];
    short8 pa1 = *(const short8*)&P[l16 * PSTR + 32 + quad * 8];
    __asm__ volatile("" ::: "memory");
#pragma unroll
    for (int dt = 0; dt < 4; dt++) {
      O[dt] = MFMA(pa0, vf[dt][0], O[dt]);
      O[dt] = MFMA(pa1, vf[dt][1], O[dt]);
    }
  }
#pragma unroll
  for (int m = 1; m < 16; m <<= 1)
#pragma unroll
    for (int r = 0; r < 4; r++) lr[r] += __shfl_xor(lr[r], m);

  int b = bh >> 4, h = bh & 15;
#pragma unroll
  for (int r = 0; r < 4; r++) {
    float inv = 1.0f / lr[r];
    size_t base = ((size_t)b * N_ + q0w + quad * 4 + r) * D_ + h * DH_;
#pragma unroll
    for (int dt = 0; dt < 4; dt++) sab[base + dt * 16 + l16] = f2bf(O[dt][r] * inv);
  }
}

// ------- output projection: 64x64 tile, BK=64, prefetch double-buffer -------
__global__ __launch_bounds__(256) void k_proj(const unsigned short* __restrict__ sab,
                                              const unsigned short* __restrict__ Wpb,
                                              const float* __restrict__ bproj,
                                              float* __restrict__ out) {
  __shared__ unsigned short Alds[2][2][64 * 32];   // [buf][kk][row][32]
  __shared__ unsigned short Blds[2][2][64 * 32];
  int t = threadIdx.x;
  int m0 = blockIdx.x * 64, c0 = blockIdx.y * 64;
  int wave = t >> 6, lane = t & 63, quad = lane >> 4, l16 = lane & 15;
  int wm = (wave >> 1) * 32, wn = (wave & 1) * 32;
  floatx4 acc[2][2];
#pragma unroll
  for (int i = 0; i < 2; i++) { acc[i][0] = (floatx4){0,0,0,0}; acc[i][1] = (floatx4){0,0,0,0}; }

  const unsigned short* gA = sab + (size_t)(m0 + wave * 16 + (lane >> 2)) * D_ + (lane & 3) * 8;
  const unsigned short* gB = Wpb + (size_t)(c0 + wave * 16 + (lane >> 2)) * D_ + (lane & 3) * 8;
  int lofs = (wave * 16) * 32;

  GL_LDS16(gA,      &Alds[0][0][lofs]);
  GL_LDS16(gA + 32, &Alds[0][1][lofs]);
  GL_LDS16(gB,      &Blds[0][0][lofs]);
  GL_LDS16(gB + 32, &Blds[0][1][lofs]);

  for (int i = 0; i < 16; i++) {
    int buf = i & 1;
    __syncthreads();
    if (i + 1 < 16) {
      int k0 = (i + 1) * 64;
      GL_LDS16(gA + k0,      &Alds[buf ^ 1][0][lofs]);
      GL_LDS16(gA + k0 + 32, &Alds[buf ^ 1][1][lofs]);
      GL_LDS16(gB + k0,      &Blds[buf ^ 1][0][lofs]);
      GL_LDS16(gB + k0 + 32, &Blds[buf ^ 1][1][lofs]);
    }
#pragma unroll
    for (int kk = 0; kk < 2; kk++) {
      short8 a[2], b[2];
#pragma unroll
      for (int mi = 0; mi < 2; mi++) a[mi] = *(const short8*)&Alds[buf][kk][(wm + mi * 16 + l16) * 32 + quad * 8];
#pragma unroll
      for (int ni = 0; ni < 2; ni++) b[ni] = *(const short8*)&Blds[buf][kk][(wn + ni * 16 + l16) * 32 + quad * 8];
#pragma unroll
      for (int mi = 0; mi < 2; mi++)
#pragma unroll
        for (int ni = 0; ni < 2; ni++) acc[mi][ni] = MFMA(a[mi], b[ni], acc[mi][ni]);
    }
  }
#pragma unroll
  for (int mi = 0; mi < 2; mi++)
#pragma unroll
    for (int ni = 0; ni < 2; ni++) {
      int col = c0 + wn + ni * 16 + l16;
      int grow = m0 + wm + mi * 16 + quad * 4;
      float bias = bproj[col];
#pragma unroll
      for (int r = 0; r < 4; r++)
        out[(size_t)(grow + r) * D_ + col] = acc[mi][ni][r] + bias;
    }
}

extern "C" void kernel_launch(void* const* d_in, const int* in_sizes, int n_in,
                              void* d_out, int out_size, void* d_ws, size_t ws_size,
                              hipStream_t stream) {
  const float* x     = (const float*)d_in[0];
  const float* Wkqv  = (const float*)d_in[1];
  const float* bkqv  = (const float*)d_in[2];
  const float* Wproj = (const float*)d_in[3];
  const float* bproj = (const float*)d_in[4];
  float* out = (float*)d_out;

  char* w = (char*)d_ws;
  unsigned short* Xb  = (unsigned short*)(w);                       // 8 MiB  [B*N][D]
  unsigned short* Wt  = (unsigned short*)(w + (8u  << 20));         // 6 MiB  [3072][1024] (cat-permuted)
  unsigned short* Wpb = (unsigned short*)(w + (14u << 20));         // 2 MiB  [D][D]
  unsigned short* Qb  = (unsigned short*)(w + (16u << 20));         // 8 MiB  [B*H][N][DH] (pre-scaled)
  unsigned short* Kb  = (unsigned short*)(w + (24u << 20));         // 8 MiB  [B*H][N][DH]
  unsigned short* Vt  = (unsigned short*)(w + (32u << 20));         // 8 MiB  [B*H][DH][N]
  unsigned short* sa  = (unsigned short*)(w + (40u << 20));         // 8 MiB  [B*N][D]

  k_prep<<<2048 + 768 + 512, 256, 0, stream>>>(x, Wkqv, Wproj, Xb, Wt, Wpb);
  k_qkv<<<dim3(B_ * N_ / 128, 3072 / 128), 256, 0, stream>>>(Xb, Wt, bkqv, Qb, Kb, Vt);
  k_flash<<<dim3(B_ * H_, N_ / 64), 256, 0, stream>>>(Qb, Kb, Vt, sa);
  k_proj<<<dim3(B_ * N_ / 64, D_ / 64), 256, 0, stream>>>(sa, Wpb, bproj, out);
}